// Round 17
// baseline (297.159 us; speedup 1.0000x reference)
//
#include <hip/hip_runtime.h>
#include <hip/hip_bf16.h>
#include <stdint.h>

// MultiHeadAttention: x[4,2048,1024] fp32, mask[4,2048] i32,
// w_qkv[3072,1024], w_tail[1024,1024], b_tail[1024] -> out[4,2048,1024] fp32
// Pipeline: fused cvt->bf16 + build_ind (global sigma-perm indicator);
// GEMM1+GEMM2 = unified 128x128 BK=32 3-buf depth-2 counted-vmcnt (3/CU);
// attn = two-tile pipeline, LDS trimmed to 48KB (sInd -> global, vi
// register-pipelined) for 3 blocks/CU.

typedef __attribute__((ext_vector_type(8))) short short8;
typedef __attribute__((ext_vector_type(4))) short short4b;
typedef __attribute__((ext_vector_type(4))) float f32x4;

#define T_SEQ 2048
#define NHEAD 16
#define DHEAD 64
#define DMODEL 1024

#if __has_builtin(__builtin_amdgcn_exp2f)
#define EXP2(x) __builtin_amdgcn_exp2f(x)
#else
#define EXP2(x) exp2f(x)
#endif

__device__ __forceinline__ ushort f2bf(float f) {
  __bf16 h = (__bf16)f;
  unsigned short u;
  __builtin_memcpy(&u, &h, 2);
  return u;
}
__device__ __forceinline__ float bf2f(ushort b) {
  return __uint_as_float(((uint32_t)b) << 16);
}

// sigma-perm within a 64-column tile; inverse (kv -> stored pos):
__device__ __forceinline__ int permInv(int x) {
  return (x & 0x23) | ((x & 0x0C) << 1) | ((x & 0x10) >> 2);
}

__device__ __forceinline__ void gload_lds16(const ushort* g, ushort* l) {
  __builtin_amdgcn_global_load_lds(
      (const __attribute__((address_space(1))) void*)g,
      (__attribute__((address_space(3))) void*)l, 16, 0, 0);
}

// ---------------- fused fp32 -> bf16 conversion (x | w_qkv | w_tail) -------
__global__ void cvt_all(const float* __restrict__ x,
                        const float* __restrict__ wq,
                        const float* __restrict__ wt,
                        ushort* __restrict__ out,
                        int n8x, int n8q, int n8t) {
  int i = blockIdx.x * blockDim.x + threadIdx.x;
  const float* src;
  int j;
  if (i < n8x) { src = x; j = i; }
  else if (i < n8x + n8q) { src = wq; j = i - n8x; }
  else if (i < n8x + n8q + n8t) { src = wt; j = i - n8x - n8q; }
  else return;
  const float4* p = (const float4*)(src + (size_t)j * 8);
  float4 a = p[0], b = p[1];
  short8 o;
  o[0] = (short)f2bf(a.x); o[1] = (short)f2bf(a.y);
  o[2] = (short)f2bf(a.z); o[3] = (short)f2bf(a.w);
  o[4] = (short)f2bf(b.x); o[5] = (short)f2bf(b.y);
  o[6] = (short)f2bf(b.z); o[7] = (short)f2bf(b.w);
  *(short8*)(out + (size_t)i * 8) = o;
}

// ---------------- build sigma-permuted bf16 keep-indicator -----------------
__global__ void build_ind(const int* __restrict__ mask,
                          ushort* __restrict__ indb) {
  int idx = blockIdx.x * blockDim.x + threadIdx.x;   // 0..8191
  int bb = idx >> 11, kv = idx & (T_SEQ - 1);
  int p = (kv & ~63) | permInv(kv & 63);
  indb[bb * T_SEQ + p] = mask[idx] ? (ushort)0x3F80 : (ushort)0;
}

// ====== GEMM: 128x128 tile, BK=32, 3-buf depth-2, 3 blocks/CU (r16) ========
template <int EPI>
__launch_bounds__(512, 6)
__global__ void gemm128(const ushort* __restrict__ A,
                        const ushort* __restrict__ B,
                        void* __restrict__ Cout,
                        const float* __restrict__ bias,
                        const int* __restrict__ msk,
                        int M, int N, int K) {
  __shared__ ushort sA[3][64 * 64];
  __shared__ ushort sB[3][64 * 64];

  const int tid = threadIdx.x;
  const int lane = tid & 63;
  const int wid = tid >> 6;
  const int wm = wid >> 2;
  const int wn = wid & 3;
  const int l15 = lane & 15;
  const int lg = lane >> 4;

  const int nbn = N >> 7;
  const int nwg = (M >> 7) * nbn;
  const int cpx = nwg >> 3;
  const int wg = (blockIdx.x & 7) * cpx + (blockIdx.x >> 3);
  const int bm = (wg / nbn) << 7;
  const int bn = (wg % nbn) << 7;

  f32x4 acc[4][2] = {};

  auto STAGE = [&](int buf, int kt) {
    {
      int c = tid;
      int line = c >> 3, slot = c & 7;
      int ls = slot ^ (line & 7);
      int row = line * 2 + (ls >> 2), ci = ls & 3;
      gload_lds16(A + (size_t)(bm + row) * K + kt * 32 + ci * 8,
                  &sA[buf][c * 8]);
    }
    {
      int c = tid;
      int line = c >> 3, slot = c & 7;
      int ls = slot ^ (line & 7);
      int row = line * 2 + (ls >> 2), ci = ls & 3;
      gload_lds16(B + (size_t)(bn + row) * K + kt * 32 + ci * 8,
                  &sB[buf][c * 8]);
    }
  };

  const int nkt = K >> 5;
  STAGE(0, 0);
  STAGE(1, 1);

  int bufT = 0;
  for (int kt = 0; kt < nkt; ++kt) {
    if (kt + 1 < nkt) {
      asm volatile("s_waitcnt vmcnt(2)" ::: "memory");
    } else {
      asm volatile("s_waitcnt vmcnt(0)" ::: "memory");
    }
    __builtin_amdgcn_sched_barrier(0);
    __builtin_amdgcn_s_barrier();
    __builtin_amdgcn_sched_barrier(0);
    if (kt + 2 < nkt) {
      int nb = bufT + 2; if (nb >= 3) nb -= 3;
      STAGE(nb, kt + 2);
    }

    short8 bfr[2];
#pragma unroll
    for (int fc = 0; fc < 2; ++fc) {
      int R = wn * 32 + fc * 16 + l15;
      int line = R >> 1;
      int sl = (((R & 1) << 2) + lg) ^ (line & 7);
      bfr[fc] = *(const short8*)&sB[bufT][line * 64 + sl * 8];
    }
    short8 af[4];
#pragma unroll
    for (int fr = 0; fr < 4; ++fr) {
      int R = wm * 64 + fr * 16 + l15;
      int line = R >> 1;
      int sl = (((R & 1) << 2) + lg) ^ (line & 7);
      af[fr] = *(const short8*)&sA[bufT][line * 64 + sl * 8];
    }
    __builtin_amdgcn_s_setprio(1);
#pragma unroll
    for (int fr = 0; fr < 4; ++fr)
#pragma unroll
      for (int fc = 0; fc < 2; ++fc)
        acc[fr][fc] = __builtin_amdgcn_mfma_f32_16x16x32_bf16(
            af[fr], bfr[fc], acc[fr][fc], 0, 0, 0);
    __builtin_amdgcn_s_setprio(0);
    bufT = (bufT + 1 == 3) ? 0 : bufT + 1;
  }

  if (EPI == 0) {
    ushort* qkvb = (ushort*)Cout;
    const int b = bm >> 11;
#pragma unroll
    for (int fr = 0; fr < 4; ++fr) {
      int mk[4];
#pragma unroll
      for (int rr = 0; rr < 4; ++rr) {
        int gr = bm + wm * 64 + fr * 16 + lg * 4 + rr;
        mk[rr] = msk[b * T_SEQ + (gr & (T_SEQ - 1))];
      }
#pragma unroll
      for (int ac = 0; ac < 2; ++ac)
#pragma unroll
        for (int rr = 0; rr < 4; ++rr) {
          int gr = bm + wm * 64 + fr * 16 + lg * 4 + rr;
          int gc = bn + wn * 32 + ac * 16 + l15;
          int t = gr & (T_SEQ - 1);
          int h = gc / 192, rem = gc - h * 192;
          int sel = rem >> 6, d = rem & 63;
          size_t base = (size_t)((b * NHEAD + h) * 3 + sel) * T_SEQ * DHEAD;
          float v = acc[fr][ac][rr];
          size_t dst;
          if (sel == 2) {
            int tp = (t & ~63) | permInv(t & 63);
            if (!mk[rr]) v = 0.f;
            dst = base + (size_t)d * T_SEQ + tp;
          } else {
            dst = base + (size_t)t * DHEAD + d;
          }
          qkvb[dst] = f2bf(v);
        }
    }
  } else {
    float* out = (float*)Cout;
#pragma unroll
    for (int fr = 0; fr < 4; ++fr)
#pragma unroll
      for (int fc = 0; fc < 2; ++fc) {
        int gc = bn + wn * 32 + fc * 16 + l15;
        float bv = bias[gc];
#pragma unroll
        for (int rr = 0; rr < 4; ++rr) {
          int gr = bm + wm * 64 + fr * 16 + lg * 4 + rr;
          out[(size_t)gr * N + gc] = acc[fr][fc][rr] + bv;
        }
      }
  }
}

// ---------------- flash attention (two-tile pipeline, 48KB LDS) ------------
// sInd removed -> LDS = 3x(8+8)KB = 48KB -> 3 blocks/CU. vi indicator
// register-pipelined from global indb (load vi(t+1) after tile t's barrier).
__launch_bounds__(256, 3)
__global__ void attn_fwd(const ushort* __restrict__ qkv,
                         const ushort* __restrict__ indb,
                         ushort* __restrict__ attn) {
  __shared__ ushort sK[3][64 * 64];
  __shared__ ushort sVT[3][64 * 64];

  const int tid = threadIdx.x;
  const int lane = tid & 63;
  const int wid = tid >> 6;
  const int l15 = lane & 15;
  const int lg = lane >> 4;
  const int bid = blockIdx.x;
  const int qt = (bid >> 3) & 15;
  const int bh = ((bid >> 7) << 3) | (bid & 7);
  const int b = bh >> 4, h = bh & 15;

  const ushort* Qp  = qkv + (size_t)(bh * 3 + 0) * T_SEQ * DHEAD;
  const ushort* Kp  = qkv + (size_t)(bh * 3 + 1) * T_SEQ * DHEAD;
  const ushort* VTp = qkv + (size_t)(bh * 3 + 2) * T_SEQ * DHEAD;
  const ushort* indp = indb + b * T_SEQ;

  const int qbase = qt * 128 + wid * 32;

  const float QSCALE = 0.18033688011112042f;
  short8 qf[2][2];
#pragma unroll
  for (int m = 0; m < 2; ++m)
#pragma unroll
    for (int ks = 0; ks < 2; ++ks) {
      short8 raw = *(const short8*)&Qp[(size_t)(qbase + m * 16 + l15) * 64 + ks * 32 + lg * 8];
#pragma unroll
      for (int e = 0; e < 8; ++e)
        qf[m][ks][e] = (short)f2bf(bf2f((ushort)raw[e]) * QSCALE);
    }

  f32x4 lacc[2] = {};
  f32x4 oacc[2][4] = {};

  auto STAGE = [&](int buf, int kt) {
    const int kb = kt * 64;
#pragma unroll
    for (int r2 = 0; r2 < 2; ++r2) {
      int c = r2 * 256 + tid;
      int row = c >> 3, ci = c & 7;
      int sb = (ci ^ (row & 7)) * 8;
      gload_lds16(Kp + (size_t)(kb + row) * 64 + sb, &sK[buf][c * 8]);
      gload_lds16(VTp + (size_t)row * T_SEQ + kb + sb, &sVT[buf][c * 8]);
    }
  };

  auto QKT = [&](int bufi, f32x4 (*st)[2]) {
    short8 kf0[4], kf1[4];
#pragma unroll
    for (int n = 0; n < 4; ++n) {
      kf0[n] = *(const short8*)&sK[bufi][(n * 16 + l15) * 64 + (((0 + lg) ^ (l15 & 7)) * 8)];
      kf1[n] = *(const short8*)&sK[bufi][(n * 16 + l15) * 64 + (((4 + lg) ^ (l15 & 7)) * 8)];
    }
    __builtin_amdgcn_s_setprio(1);
#pragma unroll
    for (int n = 0; n < 4; ++n)
#pragma unroll
      for (int m = 0; m < 2; ++m) {
        f32x4 z = {0.f, 0.f, 0.f, 0.f};
        st[n][m] = __builtin_amdgcn_mfma_f32_16x16x32_bf16(kf0[n], qf[m][0], z, 0, 0, 0);
        st[n][m] = __builtin_amdgcn_mfma_f32_16x16x32_bf16(kf1[n], qf[m][1], st[n][m], 0, 0, 0);
      }
    __builtin_amdgcn_s_setprio(0);
  };

  const int NT = T_SEQ / 64;

// VIC0/VIC1: indicator frags for tile T (consumed); VIN0/VIN1: loaded for T+1.
#define ATT_HALF(STC, STN, VIC0, VIC1, VIN0, VIN1, T, BC, BN_, BS)           \
  {                                                                          \
    _Pragma("unroll")                                                        \
    for (int m = 0; m < 2; ++m)                                              \
      _Pragma("unroll")                                                      \
      for (int n = 0; n < 4; ++n)                                            \
        _Pragma("unroll")                                                    \
        for (int r = 0; r < 4; ++r)                                          \
          STC[n][m][r] = EXP2(STC[n][m][r]);                                 \
    short8 pa[2][2];                                                         \
    _Pragma("unroll")                                                        \
    for (int m = 0; m < 2; ++m)                                              \
      _Pragma("unroll")                                                      \
      for (int ks = 0; ks < 2; ++ks)                                         \
        _Pragma("unroll")                                                    \
        for (int e = 0; e < 4; ++e) {                                        \
          pa[m][ks][e]     = (short)f2bf(STC[ks * 2][m][e]);                 \
          pa[m][ks][4 + e] = (short)f2bf(STC[ks * 2 + 1][m][e]);             \
        }                                                                    \
    asm volatile("s_waitcnt vmcnt(0)" ::: "memory");                         \
    __builtin_amdgcn_sched_barrier(0);                                       \
    __builtin_amdgcn_s_barrier();                                            \
    if ((T) + 2 < NT) STAGE(BS, (T) + 2);                                    \
    if ((T) + 1 < NT) {                                                      \
      VIN0 = *(const short8*)&indp[((T) + 1) * 64 + lg * 8];                 \
      VIN1 = *(const short8*)&indp[((T) + 1) * 64 + 32 + lg * 8];            \
      QKT(BN_, STN);                                                         \
    }                                                                        \
    _Pragma("unroll")                                                        \
    for (int ks = 0; ks < 2; ++ks) {                                         \
      short8 vf[4];                                                          \
      _Pragma("unroll")                                                      \
      for (int dt = 0; dt < 4; ++dt)                                         \
        vf[dt] = *(const short8*)&sVT[BC][(dt * 16 + l15) * 64 +             \
                 (((ks * 4 + lg) ^ (l15 & 7)) * 8)];                         \
      short8 vi = ks ? (VIC1) : (VIC0);                                      \
      __builtin_amdgcn_s_setprio(1);                                         \
      _Pragma("unroll")                                                      \
      for (int dt = 0; dt < 4; ++dt)                                         \
        _Pragma("unroll")                                                    \
        for (int m = 0; m < 2; ++m)                                          \
          oacc[m][dt] = __builtin_amdgcn_mfma_f32_16x16x32_bf16(             \
              vf[dt], pa[m][ks], oacc[m][dt], 0, 0, 0);                      \
      _Pragma("unroll")                                                      \
      for (int m = 0; m < 2; ++m)                                            \
        lacc[m] = __builtin_amdgcn_mfma_f32_16x16x32_bf16(                   \
            vi, pa[m][ks], lacc[m], 0, 0, 0);                                \
      __builtin_amdgcn_s_setprio(0);                                         \
    }                                                                        \
  }

  STAGE(0, 0);
  STAGE(1, 1);
  short8 viA0 = *(const short8*)&indp[lg * 8];
  short8 viA1 = *(const short8*)&indp[32 + lg * 8];
  short8 viB0 = {}, viB1 = {};
  __syncthreads();   // drains stages (+vi loads)

  f32x4 stA[4][2], stB[4][2];
  QKT(0, stA);

  int cur = 0;
  for (int kt = 0; kt < NT; kt += 2) {
    int b1 = cur + 1; if (b1 >= 3) b1 -= 3;
    int b2 = cur + 2; if (b2 >= 3) b2 -= 3;
    ATT_HALF(stA, stB, viA0, viA1, viB0, viB1, kt,     cur, b1, b2);
    ATT_HALF(stB, stA, viB0, viB1, viA0, viA1, kt + 1, b1,  b2, cur);
    cur = b2;
  }
#undef ATT_HALF

#pragma unroll
  for (int m = 0; m < 2; ++m) {
    float rl = 1.0f / lacc[m][0];
    int t = qbase + m * 16 + l15;
#pragma unroll
    for (int dt = 0; dt < 4; ++dt) {
      short4b ov;
#pragma unroll
      for (int r = 0; r < 4; ++r) ov[r] = (short)f2bf(oacc[m][dt][r] * rl);
      *(short4b*)&attn[(size_t)(b * T_SEQ + t) * DMODEL + h * DHEAD + dt * 16 + lg * 4] = ov;
    }
  }
}

// ---------------- launch ----------------
extern "C" void kernel_launch(void* const* d_in, const int* in_sizes, int n_in,
                              void* d_out, int out_size, void* d_ws, size_t ws_size,
                              hipStream_t stream) {
  (void)in_sizes; (void)n_in; (void)out_size; (void)ws_size;
  const float* x      = (const float*)d_in[0];  // [4,2048,1024]
  const int*   mask   = (const int*)d_in[1];    // [4,2048]
  const float* w_qkv  = (const float*)d_in[2];  // [3072,1024]
  const float* w_tail = (const float*)d_in[3];  // [1024,1024]
  const float* b_tail = (const float*)d_in[4];  // [1024]
  float* out = (float*)d_out;

  const size_t M = 4 * 2048;
  ushort* xb     = (ushort*)d_ws;                    // 8192*1024
  ushort* wqkvb  = xb + M * DMODEL;                  // 3072*1024
  ushort* wtailb = wqkvb + 3 * DMODEL * DMODEL;      // 1024*1024
  ushort* qkvb   = wtailb + DMODEL * DMODEL;         // 64*3*2048*64
  ushort* attnb  = qkvb + (size_t)64 * 3 * T_SEQ * DHEAD;  // 8192*1024
  ushort* indb   = attnb + M * DMODEL;               // 4*2048

  {
    int n8x = (int)(M * DMODEL / 8);
    int n8q = 3 * DMODEL * DMODEL / 8;
    int n8t = DMODEL * DMODEL / 8;
    int n8 = n8x + n8q + n8t;
    cvt_all<<<(n8 + 255) / 256, 256, 0, stream>>>(x, w_qkv, w_tail, xb, n8x, n8q, n8t);
  }
  build_ind<<<(4 * T_SEQ) / 256, 256, 0, stream>>>(mask, indb);

  // GEMM1 (128x128, BK=32, 3 blocks/CU): qkv = x @ w_qkv^T; grid 1536
  gemm128<0><<<dim3((M / 128) * (3 * DMODEL / 128)), 512, 0, stream>>>(
      xb, wqkvb, qkvb, nullptr, mask, (int)M, 3 * DMODEL, DMODEL);

  // attention (grid 1024, XCD-aware bh mapping, 48KB LDS -> 3 blocks/CU)
  attn_fwd<<<dim3(1024), 256, 0, stream>>>(qkvb, indb, attnb);

  // GEMM2 (128x128, BK=32, 3 blocks/CU): out = attn @ w_tail^T + b_tail; grid 512
  gemm128<1><<<dim3((M / 128) * (DMODEL / 128)), 512, 0, stream>>>(
      attnb, wtailb, out, b_tail, nullptr, (int)M, DMODEL, DMODEL);
}

// Round 18
// 221.863 us; speedup vs baseline: 1.3394x; 1.3394x over previous
//
#include <hip/hip_runtime.h>
#include <hip/hip_bf16.h>
#include <stdint.h>

// MultiHeadAttention: x[4,2048,1024] fp32, mask[4,2048] i32,
// w_qkv[3072,1024], w_tail[1024,1024], b_tail[1024] -> out[4,2048,1024] fp32
// Pipeline: fused cvt->bf16 + build_ind (global sigma-perm indicator);
// GEMM1+GEMM2 = unified 128x128 BK=32 3-buf depth-2 counted-vmcnt (3/CU);
// attn = two-tile pipeline, 48KB LDS (sInd in global, vi loaded per-tile
// inside the consuming half -- short live range, no launch_bounds cap;
// r17's ping-pong vi + (256,3) bound caused scratch spill, reverted).

typedef __attribute__((ext_vector_type(8))) short short8;
typedef __attribute__((ext_vector_type(4))) short short4b;
typedef __attribute__((ext_vector_type(4))) float f32x4;

#define T_SEQ 2048
#define NHEAD 16
#define DHEAD 64
#define DMODEL 1024

#if __has_builtin(__builtin_amdgcn_exp2f)
#define EXP2(x) __builtin_amdgcn_exp2f(x)
#else
#define EXP2(x) exp2f(x)
#endif

__device__ __forceinline__ ushort f2bf(float f) {
  __bf16 h = (__bf16)f;
  unsigned short u;
  __builtin_memcpy(&u, &h, 2);
  return u;
}
__device__ __forceinline__ float bf2f(ushort b) {
  return __uint_as_float(((uint32_t)b) << 16);
}

// sigma-perm within a 64-column tile; inverse (kv -> stored pos):
__device__ __forceinline__ int permInv(int x) {
  return (x & 0x23) | ((x & 0x0C) << 1) | ((x & 0x10) >> 2);
}

__device__ __forceinline__ void gload_lds16(const ushort* g, ushort* l) {
  __builtin_amdgcn_global_load_lds(
      (const __attribute__((address_space(1))) void*)g,
      (__attribute__((address_space(3))) void*)l, 16, 0, 0);
}

// ---------------- fused fp32 -> bf16 conversion (x | w_qkv | w_tail) -------
__global__ void cvt_all(const float* __restrict__ x,
                        const float* __restrict__ wq,
                        const float* __restrict__ wt,
                        ushort* __restrict__ out,
                        int n8x, int n8q, int n8t) {
  int i = blockIdx.x * blockDim.x + threadIdx.x;
  const float* src;
  int j;
  if (i < n8x) { src = x; j = i; }
  else if (i < n8x + n8q) { src = wq; j = i - n8x; }
  else if (i < n8x + n8q + n8t) { src = wt; j = i - n8x - n8q; }
  else return;
  const float4* p = (const float4*)(src + (size_t)j * 8);
  float4 a = p[0], b = p[1];
  short8 o;
  o[0] = (short)f2bf(a.x); o[1] = (short)f2bf(a.y);
  o[2] = (short)f2bf(a.z); o[3] = (short)f2bf(a.w);
  o[4] = (short)f2bf(b.x); o[5] = (short)f2bf(b.y);
  o[6] = (short)f2bf(b.z); o[7] = (short)f2bf(b.w);
  *(short8*)(out + (size_t)i * 8) = o;
}

// ---------------- build sigma-permuted bf16 keep-indicator -----------------
__global__ void build_ind(const int* __restrict__ mask,
                          ushort* __restrict__ indb) {
  int idx = blockIdx.x * blockDim.x + threadIdx.x;   // 0..8191
  int bb = idx >> 11, kv = idx & (T_SEQ - 1);
  int p = (kv & ~63) | permInv(kv & 63);
  indb[bb * T_SEQ + p] = mask[idx] ? (ushort)0x3F80 : (ushort)0;
}

// ====== GEMM: 128x128 tile, BK=32, 3-buf depth-2, 3 blocks/CU (r16) ========
template <int EPI>
__launch_bounds__(512, 6)
__global__ void gemm128(const ushort* __restrict__ A,
                        const ushort* __restrict__ B,
                        void* __restrict__ Cout,
                        const float* __restrict__ bias,
                        const int* __restrict__ msk,
                        int M, int N, int K) {
  __shared__ ushort sA[3][64 * 64];
  __shared__ ushort sB[3][64 * 64];

  const int tid = threadIdx.x;
  const int lane = tid & 63;
  const int wid = tid >> 6;
  const int wm = wid >> 2;
  const int wn = wid & 3;
  const int l15 = lane & 15;
  const int lg = lane >> 4;

  const int nbn = N >> 7;
  const int nwg = (M >> 7) * nbn;
  const int cpx = nwg >> 3;
  const int wg = (blockIdx.x & 7) * cpx + (blockIdx.x >> 3);
  const int bm = (wg / nbn) << 7;
  const int bn = (wg % nbn) << 7;

  f32x4 acc[4][2] = {};

  auto STAGE = [&](int buf, int kt) {
    {
      int c = tid;
      int line = c >> 3, slot = c & 7;
      int ls = slot ^ (line & 7);
      int row = line * 2 + (ls >> 2), ci = ls & 3;
      gload_lds16(A + (size_t)(bm + row) * K + kt * 32 + ci * 8,
                  &sA[buf][c * 8]);
    }
    {
      int c = tid;
      int line = c >> 3, slot = c & 7;
      int ls = slot ^ (line & 7);
      int row = line * 2 + (ls >> 2), ci = ls & 3;
      gload_lds16(B + (size_t)(bn + row) * K + kt * 32 + ci * 8,
                  &sB[buf][c * 8]);
    }
  };

  const int nkt = K >> 5;
  STAGE(0, 0);
  STAGE(1, 1);

  int bufT = 0;
  for (int kt = 0; kt < nkt; ++kt) {
    if (kt + 1 < nkt) {
      asm volatile("s_waitcnt vmcnt(2)" ::: "memory");
    } else {
      asm volatile("s_waitcnt vmcnt(0)" ::: "memory");
    }
    __builtin_amdgcn_sched_barrier(0);
    __builtin_amdgcn_s_barrier();
    __builtin_amdgcn_sched_barrier(0);
    if (kt + 2 < nkt) {
      int nb = bufT + 2; if (nb >= 3) nb -= 3;
      STAGE(nb, kt + 2);
    }

    short8 bfr[2];
#pragma unroll
    for (int fc = 0; fc < 2; ++fc) {
      int R = wn * 32 + fc * 16 + l15;
      int line = R >> 1;
      int sl = (((R & 1) << 2) + lg) ^ (line & 7);
      bfr[fc] = *(const short8*)&sB[bufT][line * 64 + sl * 8];
    }
    short8 af[4];
#pragma unroll
    for (int fr = 0; fr < 4; ++fr) {
      int R = wm * 64 + fr * 16 + l15;
      int line = R >> 1;
      int sl = (((R & 1) << 2) + lg) ^ (line & 7);
      af[fr] = *(const short8*)&sA[bufT][line * 64 + sl * 8];
    }
    __builtin_amdgcn_s_setprio(1);
#pragma unroll
    for (int fr = 0; fr < 4; ++fr)
#pragma unroll
      for (int fc = 0; fc < 2; ++fc)
        acc[fr][fc] = __builtin_amdgcn_mfma_f32_16x16x32_bf16(
            af[fr], bfr[fc], acc[fr][fc], 0, 0, 0);
    __builtin_amdgcn_s_setprio(0);
    bufT = (bufT + 1 == 3) ? 0 : bufT + 1;
  }

  if (EPI == 0) {
    ushort* qkvb = (ushort*)Cout;
    const int b = bm >> 11;
#pragma unroll
    for (int fr = 0; fr < 4; ++fr) {
      int mk[4];
#pragma unroll
      for (int rr = 0; rr < 4; ++rr) {
        int gr = bm + wm * 64 + fr * 16 + lg * 4 + rr;
        mk[rr] = msk[b * T_SEQ + (gr & (T_SEQ - 1))];
      }
#pragma unroll
      for (int ac = 0; ac < 2; ++ac)
#pragma unroll
        for (int rr = 0; rr < 4; ++rr) {
          int gr = bm + wm * 64 + fr * 16 + lg * 4 + rr;
          int gc = bn + wn * 32 + ac * 16 + l15;
          int t = gr & (T_SEQ - 1);
          int h = gc / 192, rem = gc - h * 192;
          int sel = rem >> 6, d = rem & 63;
          size_t base = (size_t)((b * NHEAD + h) * 3 + sel) * T_SEQ * DHEAD;
          float v = acc[fr][ac][rr];
          size_t dst;
          if (sel == 2) {
            int tp = (t & ~63) | permInv(t & 63);
            if (!mk[rr]) v = 0.f;
            dst = base + (size_t)d * T_SEQ + tp;
          } else {
            dst = base + (size_t)t * DHEAD + d;
          }
          qkvb[dst] = f2bf(v);
        }
    }
  } else {
    float* out = (float*)Cout;
#pragma unroll
    for (int fr = 0; fr < 4; ++fr)
#pragma unroll
      for (int fc = 0; fc < 2; ++fc) {
        int gc = bn + wn * 32 + fc * 16 + l15;
        float bv = bias[gc];
#pragma unroll
        for (int rr = 0; rr < 4; ++rr) {
          int gr = bm + wm * 64 + fr * 16 + lg * 4 + rr;
          out[(size_t)gr * N + gc] = acc[fr][fc][rr] + bv;
        }
      }
  }
}

// ---------------- flash attention (two-tile pipeline, 48KB LDS) ------------
// vi indicator loaded per-tile inside the consuming half (L2-hot 16B loads,
// ~300cy of PV work to hide under). No launch_bounds min-waves cap.
__launch_bounds__(256)
__global__ void attn_fwd(const ushort* __restrict__ qkv,
                         const ushort* __restrict__ indb,
                         ushort* __restrict__ attn) {
  __shared__ ushort sK[3][64 * 64];
  __shared__ ushort sVT[3][64 * 64];

  const int tid = threadIdx.x;
  const int lane = tid & 63;
  const int wid = tid >> 6;
  const int l15 = lane & 15;
  const int lg = lane >> 4;
  const int bid = blockIdx.x;
  const int qt = (bid >> 3) & 15;
  const int bh = ((bid >> 7) << 3) | (bid & 7);
  const int b = bh >> 4, h = bh & 15;

  const ushort* Qp  = qkv + (size_t)(bh * 3 + 0) * T_SEQ * DHEAD;
  const ushort* Kp  = qkv + (size_t)(bh * 3 + 1) * T_SEQ * DHEAD;
  const ushort* VTp = qkv + (size_t)(bh * 3 + 2) * T_SEQ * DHEAD;
  const ushort* indp = indb + b * T_SEQ;

  const int qbase = qt * 128 + wid * 32;

  const float QSCALE = 0.18033688011112042f;
  short8 qf[2][2];
#pragma unroll
  for (int m = 0; m < 2; ++m)
#pragma unroll
    for (int ks = 0; ks < 2; ++ks) {
      short8 raw = *(const short8*)&Qp[(size_t)(qbase + m * 16 + l15) * 64 + ks * 32 + lg * 8];
#pragma unroll
      for (int e = 0; e < 8; ++e)
        qf[m][ks][e] = (short)f2bf(bf2f((ushort)raw[e]) * QSCALE);
    }

  f32x4 lacc[2] = {};
  f32x4 oacc[2][4] = {};

  auto STAGE = [&](int buf, int kt) {
    const int kb = kt * 64;
#pragma unroll
    for (int r2 = 0; r2 < 2; ++r2) {
      int c = r2 * 256 + tid;
      int row = c >> 3, ci = c & 7;
      int sb = (ci ^ (row & 7)) * 8;
      gload_lds16(Kp + (size_t)(kb + row) * 64 + sb, &sK[buf][c * 8]);
      gload_lds16(VTp + (size_t)row * T_SEQ + kb + sb, &sVT[buf][c * 8]);
    }
  };

  auto QKT = [&](int bufi, f32x4 (*st)[2]) {
    short8 kf0[4], kf1[4];
#pragma unroll
    for (int n = 0; n < 4; ++n) {
      kf0[n] = *(const short8*)&sK[bufi][(n * 16 + l15) * 64 + (((0 + lg) ^ (l15 & 7)) * 8)];
      kf1[n] = *(const short8*)&sK[bufi][(n * 16 + l15) * 64 + (((4 + lg) ^ (l15 & 7)) * 8)];
    }
    __builtin_amdgcn_s_setprio(1);
#pragma unroll
    for (int n = 0; n < 4; ++n)
#pragma unroll
      for (int m = 0; m < 2; ++m) {
        f32x4 z = {0.f, 0.f, 0.f, 0.f};
        st[n][m] = __builtin_amdgcn_mfma_f32_16x16x32_bf16(kf0[n], qf[m][0], z, 0, 0, 0);
        st[n][m] = __builtin_amdgcn_mfma_f32_16x16x32_bf16(kf1[n], qf[m][1], st[n][m], 0, 0, 0);
      }
    __builtin_amdgcn_s_setprio(0);
  };

  const int NT = T_SEQ / 64;

#define ATT_HALF(STC, STN, T, BC, BN_, BS)                                   \
  {                                                                          \
    _Pragma("unroll")                                                        \
    for (int m = 0; m < 2; ++m)                                              \
      _Pragma("unroll")                                                      \
      for (int n = 0; n < 4; ++n)                                            \
        _Pragma("unroll")                                                    \
        for (int r = 0; r < 4; ++r)                                          \
          STC[n][m][r] = EXP2(STC[n][m][r]);                                 \
    short8 pa[2][2];                                                         \
    _Pragma("unroll")                                                        \
    for (int m = 0; m < 2; ++m)                                              \
      _Pragma("unroll")                                                      \
      for (int ks = 0; ks < 2; ++ks)                                         \
        _Pragma("unroll")                                                    \
        for (int e = 0; e < 4; ++e) {                                        \
          pa[m][ks][e]     = (short)f2bf(STC[ks * 2][m][e]);                 \
          pa[m][ks][4 + e] = (short)f2bf(STC[ks * 2 + 1][m][e]);             \
        }                                                                    \
    asm volatile("s_waitcnt vmcnt(0)" ::: "memory");                         \
    __builtin_amdgcn_sched_barrier(0);                                       \
    __builtin_amdgcn_s_barrier();                                            \
    if ((T) + 2 < NT) STAGE(BS, (T) + 2);                                    \
    if ((T) + 1 < NT) QKT(BN_, STN);                                         \
    short8 vi0 = *(const short8*)&indp[(T) * 64 + lg * 8];                   \
    short8 vi1 = *(const short8*)&indp[(T) * 64 + 32 + lg * 8];              \
    _Pragma("unroll")                                                        \
    for (int ks = 0; ks < 2; ++ks) {                                         \
      short8 vf[4];                                                          \
      _Pragma("unroll")                                                      \
      for (int dt = 0; dt < 4; ++dt)                                         \
        vf[dt] = *(const short8*)&sVT[BC][(dt * 16 + l15) * 64 +             \
                 (((ks * 4 + lg) ^ (l15 & 7)) * 8)];                         \
      short8 vi = ks ? vi1 : vi0;                                            \
      __builtin_amdgcn_s_setprio(1);                                         \
      _Pragma("unroll")                                                      \
      for (int dt = 0; dt < 4; ++dt)                                         \
        _Pragma("unroll")                                                    \
        for (int m = 0; m < 2; ++m)                                          \
          oacc[m][dt] = __builtin_amdgcn_mfma_f32_16x16x32_bf16(             \
              vf[dt], pa[m][ks], oacc[m][dt], 0, 0, 0);                      \
      _Pragma("unroll")                                                      \
      for (int m = 0; m < 2; ++m)                                            \
        lacc[m] = __builtin_amdgcn_mfma_f32_16x16x32_bf16(                   \
            vi, pa[m][ks], lacc[m], 0, 0, 0);                                \
      __builtin_amdgcn_s_setprio(0);                                         \
    }                                                                        \
  }

  STAGE(0, 0);
  STAGE(1, 1);
  __syncthreads();

  f32x4 stA[4][2], stB[4][2];
  QKT(0, stA);

  int cur = 0;
  for (int kt = 0; kt < NT; kt += 2) {
    int b1 = cur + 1; if (b1 >= 3) b1 -= 3;
    int b2 = cur + 2; if (b2 >= 3) b2 -= 3;
    ATT_HALF(stA, stB, kt,     cur, b1, b2);
    ATT_HALF(stB, stA, kt + 1, b1,  b2, cur);
    cur = b2;
  }
#undef ATT_HALF

#pragma unroll
  for (int m = 0; m < 2; ++m) {
    float rl = 1.0f / lacc[m][0];
    int t = qbase + m * 16 + l15;
#pragma unroll
    for (int dt = 0; dt < 4; ++dt) {
      short4b ov;
#pragma unroll
      for (int r = 0; r < 4; ++r) ov[r] = (short)f2bf(oacc[m][dt][r] * rl);
      *(short4b*)&attn[(size_t)(b * T_SEQ + t) * DMODEL + h * DHEAD + dt * 16 + lg * 4] = ov;
    }
  }
}

// ---------------- launch ----------------
extern "C" void kernel_launch(void* const* d_in, const int* in_sizes, int n_in,
                              void* d_out, int out_size, void* d_ws, size_t ws_size,
                              hipStream_t stream) {
  (void)in_sizes; (void)n_in; (void)out_size; (void)ws_size;
  const float* x      = (const float*)d_in[0];  // [4,2048,1024]
  const int*   mask   = (const int*)d_in[1];    // [4,2048]
  const float* w_qkv  = (const float*)d_in[2];  // [3072,1024]
  const float* w_tail = (const float*)d_in[3];  // [1024,1024]
  const float* b_tail = (const float*)d_in[4];  // [1024]
  float* out = (float*)d_out;

  const size_t M = 4 * 2048;
  ushort* xb     = (ushort*)d_ws;                    // 8192*1024
  ushort* wqkvb  = xb + M * DMODEL;                  // 3072*1024
  ushort* wtailb = wqkvb + 3 * DMODEL * DMODEL;      // 1024*1024
  ushort* qkvb   = wtailb + DMODEL * DMODEL;         // 64*3*2048*64
  ushort* attnb  = qkvb + (size_t)64 * 3 * T_SEQ * DHEAD;  // 8192*1024
  ushort* indb   = attnb + M * DMODEL;               // 4*2048

  {
    int n8x = (int)(M * DMODEL / 8);
    int n8q = 3 * DMODEL * DMODEL / 8;
    int n8t = DMODEL * DMODEL / 8;
    int n8 = n8x + n8q + n8t;
    cvt_all<<<(n8 + 255) / 256, 256, 0, stream>>>(x, w_qkv, w_tail, xb, n8x, n8q, n8t);
  }
  build_ind<<<(4 * T_SEQ) / 256, 256, 0, stream>>>(mask, indb);

  // GEMM1 (128x128, BK=32, 3 blocks/CU): qkv = x @ w_qkv^T; grid 1536
  gemm128<0><<<dim3((M / 128) * (3 * DMODEL / 128)), 512, 0, stream>>>(
      xb, wqkvb, qkvb, nullptr, mask, (int)M, 3 * DMODEL, DMODEL);

  // attention (grid 1024, XCD-aware bh mapping, 48KB LDS)
  attn_fwd<<<dim3(1024), 256, 0, stream>>>(qkvb, indb, attnb);

  // GEMM2 (128x128, BK=32, 3 blocks/CU): out = attn @ w_tail^T + b_tail; grid 512
  gemm128<1><<<dim3((M / 128) * (DMODEL / 128)), 512, 0, stream>>>(
      attnb, wtailb, out, b_tail, nullptr, (int)M, DMODEL, DMODEL);
}

// Round 19
// 211.442 us; speedup vs baseline: 1.4054x; 1.0493x over previous
//
#include <hip/hip_runtime.h>
#include <hip/hip_bf16.h>
#include <stdint.h>

// MultiHeadAttention: x[4,2048,1024] fp32, mask[4,2048] i32,
// w_qkv[3072,1024], w_tail[1024,1024], b_tail[1024] -> out[4,2048,1024] fp32
// FINAL (r15 best-measured config, 210.35us):
//   cvt_all -> bf16; GEMM1 = 256x128 BK=32 3-buf depth-2 counted-vmcnt
//   (2 blocks/CU), scatter Q,K [bh][t][d], V [bh][d][t'] sigma-perm+maskzero;
//   attn = r13 two-tile pipeline (swapped QK^T, in-reg P, direct exp2,
//   indicator-MFMA l, XCD remap, sInd in LDS); GEMM2 = 128x128 BK=32 (2/CU).

typedef __attribute__((ext_vector_type(8))) short short8;
typedef __attribute__((ext_vector_type(4))) short short4b;
typedef __attribute__((ext_vector_type(4))) float f32x4;

#define T_SEQ 2048
#define NHEAD 16
#define DHEAD 64
#define DMODEL 1024

#if __has_builtin(__builtin_amdgcn_exp2f)
#define EXP2(x) __builtin_amdgcn_exp2f(x)
#else
#define EXP2(x) exp2f(x)
#endif

__device__ __forceinline__ ushort f2bf(float f) {
  __bf16 h = (__bf16)f;
  unsigned short u;
  __builtin_memcpy(&u, &h, 2);
  return u;
}
__device__ __forceinline__ float bf2f(ushort b) {
  return __uint_as_float(((uint32_t)b) << 16);
}

// sigma-perm within a 64-column tile; inverse (kv -> stored pos):
__device__ __forceinline__ int permInv(int x) {
  return (x & 0x23) | ((x & 0x0C) << 1) | ((x & 0x10) >> 2);
}

__device__ __forceinline__ void gload_lds16(const ushort* g, ushort* l) {
  __builtin_amdgcn_global_load_lds(
      (const __attribute__((address_space(1))) void*)g,
      (__attribute__((address_space(3))) void*)l, 16, 0, 0);
}

// ---------------- fused fp32 -> bf16 conversion (x | w_qkv | w_tail) -------
__global__ void cvt_all(const float* __restrict__ x,
                        const float* __restrict__ wq,
                        const float* __restrict__ wt,
                        ushort* __restrict__ out,
                        int n8x, int n8q, int n8t) {
  int i = blockIdx.x * blockDim.x + threadIdx.x;
  const float* src;
  int j;
  if (i < n8x) { src = x; j = i; }
  else if (i < n8x + n8q) { src = wq; j = i - n8x; }
  else if (i < n8x + n8q + n8t) { src = wt; j = i - n8x - n8q; }
  else return;
  const float4* p = (const float4*)(src + (size_t)j * 8);
  float4 a = p[0], b = p[1];
  short8 o;
  o[0] = (short)f2bf(a.x); o[1] = (short)f2bf(a.y);
  o[2] = (short)f2bf(a.z); o[3] = (short)f2bf(a.w);
  o[4] = (short)f2bf(b.x); o[5] = (short)f2bf(b.y);
  o[6] = (short)f2bf(b.z); o[7] = (short)f2bf(b.w);
  *(short8*)(out + (size_t)i * 8) = o;
}

// ====== GEMM1: 256x128 tile, BK=32, 3-buf depth-2, 2 blocks/CU =============
__launch_bounds__(512, 4)
__global__ void gemm1_32(const ushort* __restrict__ A,
                         const ushort* __restrict__ B,
                         ushort* __restrict__ qkvb,
                         const int* __restrict__ msk,
                         int M, int N, int K) {
  __shared__ ushort sA[3][128 * 64];
  __shared__ ushort sB[3][64 * 64];

  const int tid = threadIdx.x;
  const int lane = tid & 63;
  const int wid = tid >> 6;
  const int wm = wid >> 2;
  const int wn = wid & 3;
  const int l15 = lane & 15;
  const int lg = lane >> 4;

  const int nbn = N >> 7;
  const int nwg = (M >> 8) * nbn;
  const int cpx = nwg >> 3;
  const int wg = (blockIdx.x & 7) * cpx + (blockIdx.x >> 3);
  const int bm = (wg / nbn) << 8;
  const int bn = (wg % nbn) << 7;

  f32x4 acc[8][2] = {};

  auto STAGE = [&](int buf, int kt) {
#pragma unroll
    for (int r = 0; r < 2; ++r) {
      int c = r * 512 + tid;
      int line = c >> 3, slot = c & 7;
      int ls = slot ^ (line & 7);
      int row = line * 2 + (ls >> 2), ci = ls & 3;
      gload_lds16(A + (size_t)(bm + row) * K + kt * 32 + ci * 8,
                  &sA[buf][c * 8]);
    }
    {
      int c = tid;
      int line = c >> 3, slot = c & 7;
      int ls = slot ^ (line & 7);
      int row = line * 2 + (ls >> 2), ci = ls & 3;
      gload_lds16(B + (size_t)(bn + row) * K + kt * 32 + ci * 8,
                  &sB[buf][c * 8]);
    }
  };

  const int nkt = K >> 5;
  STAGE(0, 0);
  STAGE(1, 1);

  int bufT = 0;
  for (int kt = 0; kt < nkt; ++kt) {
    if (kt + 1 < nkt) {
      asm volatile("s_waitcnt vmcnt(3)" ::: "memory");
    } else {
      asm volatile("s_waitcnt vmcnt(0)" ::: "memory");
    }
    __builtin_amdgcn_sched_barrier(0);
    __builtin_amdgcn_s_barrier();
    __builtin_amdgcn_sched_barrier(0);
    if (kt + 2 < nkt) {
      int nb = bufT + 2; if (nb >= 3) nb -= 3;
      STAGE(nb, kt + 2);
    }

    short8 bfr[2];
#pragma unroll
    for (int fc = 0; fc < 2; ++fc) {
      int R = wn * 32 + fc * 16 + l15;
      int line = R >> 1;
      int sl = (((R & 1) << 2) + lg) ^ (line & 7);
      bfr[fc] = *(const short8*)&sB[bufT][line * 64 + sl * 8];
    }
#pragma unroll
    for (int QQ = 0; QQ < 2; ++QQ) {
      short8 af[4];
#pragma unroll
      for (int fr = 0; fr < 4; ++fr) {
        int R = wm * 128 + (QQ * 4 + fr) * 16 + l15;
        int line = R >> 1;
        int sl = (((R & 1) << 2) + lg) ^ (line & 7);
        af[fr] = *(const short8*)&sA[bufT][line * 64 + sl * 8];
      }
      __builtin_amdgcn_s_setprio(1);
#pragma unroll
      for (int fr = 0; fr < 4; ++fr)
#pragma unroll
        for (int fc = 0; fc < 2; ++fc)
          acc[QQ * 4 + fr][fc] = __builtin_amdgcn_mfma_f32_16x16x32_bf16(
              af[fr], bfr[fc], acc[QQ * 4 + fr][fc], 0, 0, 0);
      __builtin_amdgcn_s_setprio(0);
    }
    bufT = (bufT + 1 == 3) ? 0 : bufT + 1;
  }

  const int b = bm >> 11;
#pragma unroll
  for (int ar = 0; ar < 8; ++ar) {
    int mk[4];
#pragma unroll
    for (int rr = 0; rr < 4; ++rr) {
      int gr = bm + wm * 128 + ar * 16 + lg * 4 + rr;
      mk[rr] = msk[b * T_SEQ + (gr & (T_SEQ - 1))];
    }
#pragma unroll
    for (int ac = 0; ac < 2; ++ac)
#pragma unroll
      for (int rr = 0; rr < 4; ++rr) {
        int gr = bm + wm * 128 + ar * 16 + lg * 4 + rr;
        int gc = bn + wn * 32 + ac * 16 + l15;
        int t = gr & (T_SEQ - 1);
        int h = gc / 192, rem = gc - h * 192;
        int sel = rem >> 6, d = rem & 63;
        size_t base = (size_t)((b * NHEAD + h) * 3 + sel) * T_SEQ * DHEAD;
        float v = acc[ar][ac][rr];
        size_t dst;
        if (sel == 2) {
          int tp = (t & ~63) | permInv(t & 63);
          if (!mk[rr]) v = 0.f;
          dst = base + (size_t)d * T_SEQ + tp;
        } else {
          dst = base + (size_t)t * DHEAD + d;
        }
        qkvb[dst] = f2bf(v);
      }
  }
}

// ====== GEMM2: 128x128 tile, BK=32, 3-buf depth-2, 2 blocks/CU =============
__launch_bounds__(512, 4)
__global__ void gemm2_128(const ushort* __restrict__ A,
                          const ushort* __restrict__ B,
                          float* __restrict__ Cout,
                          const float* __restrict__ bias,
                          int M, int N, int K) {
  __shared__ ushort sA[3][64 * 64];
  __shared__ ushort sB[3][64 * 64];

  const int tid = threadIdx.x;
  const int lane = tid & 63;
  const int wid = tid >> 6;
  const int wm = wid >> 2;
  const int wn = wid & 3;
  const int l15 = lane & 15;
  const int lg = lane >> 4;

  const int nbn = N >> 7;
  const int nwg = (M >> 7) * nbn;
  const int cpx = nwg >> 3;
  const int wg = (blockIdx.x & 7) * cpx + (blockIdx.x >> 3);
  const int bm = (wg / nbn) << 7;
  const int bn = (wg % nbn) << 7;

  f32x4 acc[4][2] = {};

  auto STAGE = [&](int buf, int kt) {
    {
      int c = tid;
      int line = c >> 3, slot = c & 7;
      int ls = slot ^ (line & 7);
      int row = line * 2 + (ls >> 2), ci = ls & 3;
      gload_lds16(A + (size_t)(bm + row) * K + kt * 32 + ci * 8,
                  &sA[buf][c * 8]);
    }
    {
      int c = tid;
      int line = c >> 3, slot = c & 7;
      int ls = slot ^ (line & 7);
      int row = line * 2 + (ls >> 2), ci = ls & 3;
      gload_lds16(B + (size_t)(bn + row) * K + kt * 32 + ci * 8,
                  &sB[buf][c * 8]);
    }
  };

  const int nkt = K >> 5;
  STAGE(0, 0);
  STAGE(1, 1);

  int bufT = 0;
  for (int kt = 0; kt < nkt; ++kt) {
    if (kt + 1 < nkt) {
      asm volatile("s_waitcnt vmcnt(2)" ::: "memory");
    } else {
      asm volatile("s_waitcnt vmcnt(0)" ::: "memory");
    }
    __builtin_amdgcn_sched_barrier(0);
    __builtin_amdgcn_s_barrier();
    __builtin_amdgcn_sched_barrier(0);
    if (kt + 2 < nkt) {
      int nb = bufT + 2; if (nb >= 3) nb -= 3;
      STAGE(nb, kt + 2);
    }

    short8 bfr[2];
#pragma unroll
    for (int fc = 0; fc < 2; ++fc) {
      int R = wn * 32 + fc * 16 + l15;
      int line = R >> 1;
      int sl = (((R & 1) << 2) + lg) ^ (line & 7);
      bfr[fc] = *(const short8*)&sB[bufT][line * 64 + sl * 8];
    }
    short8 af[4];
#pragma unroll
    for (int fr = 0; fr < 4; ++fr) {
      int R = wm * 64 + fr * 16 + l15;
      int line = R >> 1;
      int sl = (((R & 1) << 2) + lg) ^ (line & 7);
      af[fr] = *(const short8*)&sA[bufT][line * 64 + sl * 8];
    }
    __builtin_amdgcn_s_setprio(1);
#pragma unroll
    for (int fr = 0; fr < 4; ++fr)
#pragma unroll
      for (int fc = 0; fc < 2; ++fc)
        acc[fr][fc] = __builtin_amdgcn_mfma_f32_16x16x32_bf16(
            af[fr], bfr[fc], acc[fr][fc], 0, 0, 0);
    __builtin_amdgcn_s_setprio(0);
    bufT = (bufT + 1 == 3) ? 0 : bufT + 1;
  }

#pragma unroll
  for (int fr = 0; fr < 4; ++fr)
#pragma unroll
    for (int fc = 0; fc < 2; ++fc) {
      int gc = bn + wn * 32 + fc * 16 + l15;
      float bv = bias[gc];
#pragma unroll
      for (int rr = 0; rr < 4; ++rr) {
        int gr = bm + wm * 64 + fr * 16 + lg * 4 + rr;
        Cout[(size_t)gr * N + gc] = acc[fr][fc][rr] + bv;
      }
    }
}

// ---------------- flash attention (two-tile pipeline, r13 exact) -----------
__launch_bounds__(256)
__global__ void attn_fwd(const ushort* __restrict__ qkv,
                         const int* __restrict__ mask,
                         ushort* __restrict__ attn) {
  __shared__ ushort sK[3][64 * 64];
  __shared__ ushort sVT[3][64 * 64];
  __shared__ ushort sInd[T_SEQ];

  const int tid = threadIdx.x;
  const int lane = tid & 63;
  const int wid = tid >> 6;
  const int l15 = lane & 15;
  const int lg = lane >> 4;
  const int bid = blockIdx.x;
  const int qt = (bid >> 3) & 15;
  const int bh = ((bid >> 7) << 3) | (bid & 7);
  const int b = bh >> 4, h = bh & 15;

  const ushort* Qp  = qkv + (size_t)(bh * 3 + 0) * T_SEQ * DHEAD;
  const ushort* Kp  = qkv + (size_t)(bh * 3 + 1) * T_SEQ * DHEAD;
  const ushort* VTp = qkv + (size_t)(bh * 3 + 2) * T_SEQ * DHEAD;
  const int* mrow = mask + b * T_SEQ;

  const int qbase = qt * 128 + wid * 32;

#pragma unroll
  for (int e = 0; e < 8; ++e) {
    int kv = tid * 8 + e;
    int p = (kv & ~63) | permInv(kv & 63);
    sInd[p] = mrow[kv] ? (ushort)0x3F80 : (ushort)0;
  }

  const float QSCALE = 0.18033688011112042f;
  short8 qf[2][2];
#pragma unroll
  for (int m = 0; m < 2; ++m)
#pragma unroll
    for (int ks = 0; ks < 2; ++ks) {
      short8 raw = *(const short8*)&Qp[(size_t)(qbase + m * 16 + l15) * 64 + ks * 32 + lg * 8];
#pragma unroll
      for (int e = 0; e < 8; ++e)
        qf[m][ks][e] = (short)f2bf(bf2f((ushort)raw[e]) * QSCALE);
    }

  f32x4 lacc[2] = {};
  f32x4 oacc[2][4] = {};

  auto STAGE = [&](int buf, int kt) {
    const int kb = kt * 64;
#pragma unroll
    for (int r2 = 0; r2 < 2; ++r2) {
      int c = r2 * 256 + tid;
      int row = c >> 3, ci = c & 7;
      int sb = (ci ^ (row & 7)) * 8;
      gload_lds16(Kp + (size_t)(kb + row) * 64 + sb, &sK[buf][c * 8]);
      gload_lds16(VTp + (size_t)row * T_SEQ + kb + sb, &sVT[buf][c * 8]);
    }
  };

  auto QKT = [&](int bufi, f32x4 (*st)[2]) {
    short8 kf0[4], kf1[4];
#pragma unroll
    for (int n = 0; n < 4; ++n) {
      kf0[n] = *(const short8*)&sK[bufi][(n * 16 + l15) * 64 + (((0 + lg) ^ (l15 & 7)) * 8)];
      kf1[n] = *(const short8*)&sK[bufi][(n * 16 + l15) * 64 + (((4 + lg) ^ (l15 & 7)) * 8)];
    }
    __builtin_amdgcn_s_setprio(1);
#pragma unroll
    for (int n = 0; n < 4; ++n)
#pragma unroll
      for (int m = 0; m < 2; ++m) {
        f32x4 z = {0.f, 0.f, 0.f, 0.f};
        st[n][m] = __builtin_amdgcn_mfma_f32_16x16x32_bf16(kf0[n], qf[m][0], z, 0, 0, 0);
        st[n][m] = __builtin_amdgcn_mfma_f32_16x16x32_bf16(kf1[n], qf[m][1], st[n][m], 0, 0, 0);
      }
    __builtin_amdgcn_s_setprio(0);
  };

  const int NT = T_SEQ / 64;

#define ATT_HALF(STC, STN, T, BC, BN_, BS)                                   \
  {                                                                          \
    _Pragma("unroll")                                                        \
    for (int m = 0; m < 2; ++m)                                              \
      _Pragma("unroll")                                                      \
      for (int n = 0; n < 4; ++n)                                            \
        _Pragma("unroll")                                                    \
        for (int r = 0; r < 4; ++r)                                          \
          STC[n][m][r] = EXP2(STC[n][m][r]);                                 \
    short8 pa[2][2];                                                         \
    _Pragma("unroll")                                                        \
    for (int m = 0; m < 2; ++m)                                              \
      _Pragma("unroll")                                                      \
      for (int ks = 0; ks < 2; ++ks)                                         \
        _Pragma("unroll")                                                    \
        for (int e = 0; e < 4; ++e) {                                        \
          pa[m][ks][e]     = (short)f2bf(STC[ks * 2][m][e]);                 \
          pa[m][ks][4 + e] = (short)f2bf(STC[ks * 2 + 1][m][e]);             \
        }                                                                    \
    asm volatile("s_waitcnt vmcnt(0)" ::: "memory");                         \
    __builtin_amdgcn_sched_barrier(0);                                       \
    __builtin_amdgcn_s_barrier();                                            \
    if ((T) + 2 < NT) STAGE(BS, (T) + 2);                                    \
    if ((T) + 1 < NT) QKT(BN_, STN);                                         \
    _Pragma("unroll")                                                        \
    for (int ks = 0; ks < 2; ++ks) {                                         \
      short8 vf[4];                                                          \
      _Pragma("unroll")                                                      \
      for (int dt = 0; dt < 4; ++dt)                                         \
        vf[dt] = *(const short8*)&sVT[BC][(dt * 16 + l15) * 64 +             \
                 (((ks * 4 + lg) ^ (l15 & 7)) * 8)];                         \
      short8 vi = *(const short8*)&sInd[(T) * 64 + ks * 32 + lg * 8];        \
      __builtin_amdgcn_s_setprio(1);                                         \
      _Pragma("unroll")                                                      \
      for (int dt = 0; dt < 4; ++dt)                                         \
        _Pragma("unroll")                                                    \
        for (int m = 0; m < 2; ++m)                                          \
          oacc[m][dt] = __builtin_amdgcn_mfma_f32_16x16x32_bf16(             \
              vf[dt], pa[m][ks], oacc[m][dt], 0, 0, 0);                      \
      _Pragma("unroll")                                                      \
      for (int m = 0; m < 2; ++m)                                            \
        lacc[m] = __builtin_amdgcn_mfma_f32_16x16x32_bf16(                   \
            vi, pa[m][ks], lacc[m], 0, 0, 0);                                \
      __builtin_amdgcn_s_setprio(0);                                         \
    }                                                                        \
  }

  STAGE(0, 0);
  STAGE(1, 1);
  __syncthreads();

  f32x4 stA[4][2], stB[4][2];
  QKT(0, stA);

  int cur = 0;
  for (int kt = 0; kt < NT; kt += 2) {
    int b1 = cur + 1; if (b1 >= 3) b1 -= 3;
    int b2 = cur + 2; if (b2 >= 3) b2 -= 3;
    ATT_HALF(stA, stB, kt,     cur, b1, b2);
    ATT_HALF(stB, stA, kt + 1, b1,  b2, cur);
    cur = b2;
  }
#undef ATT_HALF

#pragma unroll
  for (int m = 0; m < 2; ++m) {
    float rl = 1.0f / lacc[m][0];
    int t = qbase + m * 16 + l15;
#pragma unroll
    for (int dt = 0; dt < 4; ++dt) {
      short4b ov;
#pragma unroll
      for (int r = 0; r < 4; ++r) ov[r] = (short)f2bf(oacc[m][dt][r] * rl);
      *(short4b*)&attn[(size_t)(b * T_SEQ + t) * DMODEL + h * DHEAD + dt * 16 + lg * 4] = ov;
    }
  }
}

// ---------------- launch ----------------
extern "C" void kernel_launch(void* const* d_in, const int* in_sizes, int n_in,
                              void* d_out, int out_size, void* d_ws, size_t ws_size,
                              hipStream_t stream) {
  (void)in_sizes; (void)n_in; (void)out_size; (void)ws_size;
  const float* x      = (const float*)d_in[0];  // [4,2048,1024]
  const int*   mask   = (const int*)d_in[1];    // [4,2048]
  const float* w_qkv  = (const float*)d_in[2];  // [3072,1024]
  const float* w_tail = (const float*)d_in[3];  // [1024,1024]
  const float* b_tail = (const float*)d_in[4];  // [1024]
  float* out = (float*)d_out;

  const size_t M = 4 * 2048;
  ushort* xb     = (ushort*)d_ws;                    // 8192*1024
  ushort* wqkvb  = xb + M * DMODEL;                  // 3072*1024
  ushort* wtailb = wqkvb + 3 * DMODEL * DMODEL;      // 1024*1024
  ushort* qkvb   = wtailb + DMODEL * DMODEL;         // 64*3*2048*64
  ushort* attnb  = qkvb + (size_t)64 * 3 * T_SEQ * DHEAD;  // 8192*1024

  {
    int n8x = (int)(M * DMODEL / 8);
    int n8q = 3 * DMODEL * DMODEL / 8;
    int n8t = DMODEL * DMODEL / 8;
    int n8 = n8x + n8q + n8t;
    cvt_all<<<(n8 + 255) / 256, 256, 0, stream>>>(x, w_qkv, w_tail, xb, n8x, n8q, n8t);
  }

  // GEMM1 (256x128, BK=32, 2 blocks/CU): qkv = x @ w_qkv^T; grid 768
  gemm1_32<<<dim3((M / 256) * (3 * DMODEL / 128)), 512, 0, stream>>>(
      xb, wqkvb, qkvb, mask, (int)M, 3 * DMODEL, DMODEL);

  // attention (grid 1024, XCD-aware bh mapping) — r13 version
  attn_fwd<<<dim3(1024), 256, 0, stream>>>(qkvb, mask, attnb);

  // GEMM2 (128x128, BK=32, 2 blocks/CU): out = attn @ w_tail^T + b_tail; grid 512
  gemm2_128<<<dim3((M / 128) * (DMODEL / 128)), 512, 0, stream>>>(
      attnb, wtailb, out, b_tail, (int)M, DMODEL, DMODEL);
}